// Round 9
// baseline (974.371 us; speedup 1.0000x reference)
//
#include <hip/hip_runtime.h>
#include <hip/hip_bf16.h>

typedef __bf16 bf16x8_v __attribute__((ext_vector_type(8)));
typedef float  f32x4_v  __attribute__((ext_vector_type(4)));

static constexpr int kH = 1024;
static constexpr int kD = 2048;   // 2H
static constexpr int kB = 64;
static constexpr int kS = 2048;
static constexpr int kM = kB * kS;  // 131072 rows of the big GEMM

__device__ __forceinline__ void load_lds16(const void* g, void* l) {
  __builtin_amdgcn_global_load_lds(
      (const __attribute__((address_space(1))) unsigned int*)g,
      (__attribute__((address_space(3))) unsigned int*)l, 16, 0, 0);
}

__device__ __forceinline__ float fast_tanh(float x) {
  float e = __expf(2.0f * x);
  return 1.0f - 2.0f * __builtin_amdgcn_rcpf(e + 1.0f);
}

// ---- fp32 row-major [rows][2048] -> bf16 tiled ------------------------------
// Tile = 16 rows x 32 cols. Output: [row/16][kt=0..63][64 chunks of 16B].
// Chunk p: rr = p>>2, s = p&3; slot s holds k-chunk c = s ^ ((rr>>1)&3).
__global__ __launch_bounds__(256) void conv_tile_kernel(const float* __restrict__ in,
                                                        __bf16* __restrict__ out) {
  size_t g = (size_t)blockIdx.x * 256 + threadIdx.x;
  int p = (int)(g & 63);
  size_t tile = g >> 6;
  int kt = (int)(tile & 63);
  size_t mt16 = tile >> 6;
  int rr = p >> 2, s = p & 3;
  int c = s ^ ((rr >> 1) & 3);
  const float* src = in + (mt16 * 16 + rr) * (size_t)kD + kt * 32 + c * 8;
  float4 v0 = reinterpret_cast<const float4*>(src)[0];
  float4 v1 = reinterpret_cast<const float4*>(src)[1];
  bf16x8_v o = {(__bf16)v0.x, (__bf16)v0.y, (__bf16)v0.z, (__bf16)v0.w,
                (__bf16)v1.x, (__bf16)v1.y, (__bf16)v1.z, (__bf16)v1.w};
  reinterpret_cast<bf16x8_v*>(out)[g] = o;
}

// ------------- biasBH[b][h] = s_t[b] . W_s[h] + b_s[h] + b_h[h] -------------
__global__ __launch_bounds__(256) void prep_bias_kernel(
    const float* __restrict__ s_t, const float* __restrict__ W_s,
    const float* __restrict__ b_s, const float* __restrict__ b_h,
    float* __restrict__ biasBH) {
  int wave = blockIdx.x * 4 + (threadIdx.x >> 6);  // 65536 outputs
  int lane = threadIdx.x & 63;
  int b = wave >> 10, h = wave & 1023;
  const float4* sp = reinterpret_cast<const float4*>(s_t + (size_t)b * kD);
  const float4* wp = reinterpret_cast<const float4*>(W_s + (size_t)h * kD);
  float acc = 0.f;
  for (int i = lane; i < kD / 4; i += 64) {
    float4 a = sp[i], w = wp[i];
    acc += a.x * w.x + a.y * w.y + a.z * w.z + a.w * w.w;
  }
  for (int m = 1; m < 64; m <<= 1) acc += __shfl_xor(acc, m);
  if (lane == 0) biasBH[wave] = acc + b_s[h] + b_h[h];
}

// ---------------- big GEMM + fused tanh/v_a epilogue -> E -------------------
// BM=128, BN=128, BK=32 (64 steps), 4 waves (2x2), per-wave 64x64.
// A: tiled bf16 via global_load_lds, 3-deep LDS (24 KB), staged AFTER the
//    barrier (write-after-read safe by buffer distance).
// B: tiled bf16 read DIRECTLY global->VGPR (L2-resident 4 MB), prefetched one
//    step ahead into named double regs. No B in LDS at all.
// One barrier per step; counted vmcnt(6) (tail 0); never a mid-loop drain.
__global__ __launch_bounds__(256, 3) void gemm_score_kernel(
    const __bf16* __restrict__ Atl,     // tiled bf16 A for this chunk
    const __bf16* __restrict__ Btl,     // tiled bf16 W_h
    const float* __restrict__ biasBH,   // (kB, kH)
    const float* __restrict__ coverage, // (kB, kS)
    const float* __restrict__ Wc,       // (kH)
    const float* __restrict__ va,       // (kH)
    float* __restrict__ E,              // (kB, kS), pre-zeroed
    int mrow0) {                        // global row offset of this chunk
  const int bid = blockIdx.x;
  const int mtiles = gridDim.x >> 3;    // 128-row M-tiles in this chunk (mult of 8)
  const int mpx = mtiles >> 3;
  const int xcd = bid & 7;
  const int slot = bid >> 3;
  const int m_l = xcd * mpx + (slot >> 3);  // XCD-partitioned, n fastest
  const int n0 = (slot & 7) * 128;
  const int m0l = m_l * 128;            // chunk-local row base
  const int m0g = mrow0 + m0l;          // global row base

  const int tid = threadIdx.x;
  const int lane = tid & 63;
  const int wid = tid >> 6;             // 0..3
  const int wm = wid >> 1, wn = wid & 1;

  __shared__ char lds[3 * 8192];        // A triple buffer

  f32x4_v acc[4][4];
#pragma unroll
  for (int m = 0; m < 4; ++m)
#pragma unroll
    for (int n = 0; n < 4; ++n) acc[m][n] = {0.f, 0.f, 0.f, 0.f};

  const int rA = wm * 64 + (lane & 15);
  const int slot16 = (((lane >> 4) ^ ((lane >> 1) & 3)) << 4);
  const int rrl = lane & 15;
  const int j = lane >> 4;

  const size_t mt16b = (size_t)(m0l >> 4);
  // A staging: wave stages subtiles wid*2, wid*2+1 (16 rows x 32 cols each)
  const __bf16* Asrc0 = Atl + ((mt16b + wid * 2) * 64) * 512 + lane * 8;
  const __bf16* Asrc1 = Atl + ((mt16b + wid * 2 + 1) * 64) * 512 + lane * 8;
  char* Adst0base = lds + (wid * 2) * 1024 + lane * 16;
  char* Adst1base = lds + (wid * 2 + 1) * 1024 + lane * 16;

  // B per-lane fragment pointers (4, one per n)
  const int hn = n0 + wn * 64 + rrl;
  const int loff = (rrl * 4 + (j ^ ((rrl >> 1) & 3))) * 8;
  const __bf16* Bp0 = Btl + (size_t)(((hn >> 4) + 0) * 64) * 512 + loff;
  const __bf16* Bp1 = Btl + (size_t)(((hn >> 4) + 1) * 64) * 512 + loff;
  const __bf16* Bp2 = Btl + (size_t)(((hn >> 4) + 2) * 64) * 512 + loff;
  const __bf16* Bp3 = Btl + (size_t)(((hn >> 4) + 3) * 64) * 512 + loff;

  bf16x8_v b0[4], b1[4];

#define STAGE_A(T)                                                   \
  do {                                                               \
    int boff = ((T) % 3) * 8192;                                     \
    load_lds16(Asrc0 + (size_t)(T) * 512, Adst0base + boff);         \
    load_lds16(Asrc1 + (size_t)(T) * 512, Adst1base + boff);         \
  } while (0)

#define LOADB(T, BD)                                                 \
  do {                                                               \
    BD[0] = *reinterpret_cast<const bf16x8_v*>(Bp0 + (size_t)(T) * 512); \
    BD[1] = *reinterpret_cast<const bf16x8_v*>(Bp1 + (size_t)(T) * 512); \
    BD[2] = *reinterpret_cast<const bf16x8_v*>(Bp2 + (size_t)(T) * 512); \
    BD[3] = *reinterpret_cast<const bf16x8_v*>(Bp3 + (size_t)(T) * 512); \
  } while (0)

#define ITER(T, BC, BN, DO_LOADB, WAITN, DO_STAGE)                   \
  do {                                                               \
    if (DO_LOADB) LOADB((T) + 1, BN);                                \
    __builtin_amdgcn_sched_barrier(0);                               \
    asm volatile("s_waitcnt vmcnt(" #WAITN ")" ::: "memory");        \
    __builtin_amdgcn_s_barrier();                                    \
    __builtin_amdgcn_sched_barrier(0);                               \
    if (DO_STAGE) STAGE_A((T) + 2);                                  \
    const char* Ab = lds + ((T) % 3) * 8192;                         \
    bf16x8_v a[4];                                                   \
    _Pragma("unroll")                                                \
    for (int m = 0; m < 4; ++m)                                      \
      a[m] = *reinterpret_cast<const bf16x8_v*>(Ab + (rA + m * 16) * 64 + slot16); \
    __builtin_amdgcn_s_setprio(1);                                   \
    _Pragma("unroll")                                                \
    for (int m = 0; m < 4; ++m)                                      \
      _Pragma("unroll")                                              \
      for (int n = 0; n < 4; ++n)                                    \
        acc[m][n] = __builtin_amdgcn_mfma_f32_16x16x32_bf16(a[m], BC[n], acc[m][n], 0, 0, 0); \
    __builtin_amdgcn_s_setprio(0);                                   \
  } while (0)

  // prologue: A(0), A(1) staged; B(0) in b0
  STAGE_A(0);
  STAGE_A(1);
  LOADB(0, b0);

  for (int t = 0; t < 62; t += 2) {
    ITER(t, b0, b1, 1, 6, 1);
    ITER(t + 1, b1, b0, 1, 6, 1);
  }
  ITER(62, b0, b1, 1, 6, 0);
  ITER(63, b1, b0, 0, 0, 0);

#undef STAGE_A
#undef LOADB
#undef ITER

  // ---- epilogue: z = acc + bias + cov*Wc; E_partial = sum_h tanh(z)*va[h]
  const int bb = m0g >> 11;             // batch (uniform per block)
  const int colg = lane & 15;
  const int rowg = lane >> 4;           // 0..3
  float bias_v[4], wc_v[4], va_v[4];
#pragma unroll
  for (int n = 0; n < 4; ++n) {
    int h = n0 + wn * 64 + n * 16 + colg;
    bias_v[n] = biasBH[bb * kH + h];
    wc_v[n] = Wc[h];
    va_v[n] = va[h];
  }
  const int s_tile = (m0g & (kS - 1));
  float rowsum[4][4];
#pragma unroll
  for (int m = 0; m < 4; ++m)
#pragma unroll
    for (int q = 0; q < 4; ++q) rowsum[m][q] = 0.f;

#pragma unroll
  for (int m = 0; m < 4; ++m) {
    int sbase = s_tile + wm * 64 + m * 16 + rowg * 4;
    float cov[4];
#pragma unroll
    for (int q = 0; q < 4; ++q) cov[q] = coverage[bb * kS + sbase + q];
#pragma unroll
    for (int n = 0; n < 4; ++n) {
#pragma unroll
      for (int q = 0; q < 4; ++q) {
        float z = acc[m][n][q] + bias_v[n] + cov[q] * wc_v[n];
        rowsum[m][q] += fast_tanh(z) * va_v[n];
      }
    }
  }
#pragma unroll
  for (int m = 0; m < 4; ++m) {
#pragma unroll
    for (int q = 0; q < 4; ++q) {
      float v = rowsum[m][q];
      v += __shfl_xor(v, 1);
      v += __shfl_xor(v, 2);
      v += __shfl_xor(v, 4);
      v += __shfl_xor(v, 8);
      if (colg == 0) {
        int s = s_tile + wm * 64 + m * 16 + rowg * 4 + q;
        atomicAdd(&E[bb * kS + s], v);
      }
    }
  }
}

// ---------------- softmax over S per (b); A and new_cov ---------------------
__global__ __launch_bounds__(256) void softmax_kernel(
    const float* __restrict__ E, const float* __restrict__ coverage,
    float* __restrict__ A, float* __restrict__ newcov) {
  int b = blockIdx.x;
  int tid = threadIdx.x;
  int wid = tid >> 6, lane = tid & 63;
  __shared__ float wred[4];
  float ev[8];
  float mx = -INFINITY;
#pragma unroll
  for (int i = 0; i < 8; ++i) {
    ev[i] = E[b * kS + tid + i * 256];
    mx = fmaxf(mx, ev[i]);
  }
  for (int m = 1; m < 64; m <<= 1) mx = fmaxf(mx, __shfl_xor(mx, m));
  if (lane == 0) wred[wid] = mx;
  __syncthreads();
  mx = fmaxf(fmaxf(wred[0], wred[1]), fmaxf(wred[2], wred[3]));
  __syncthreads();
  float sum = 0.f;
#pragma unroll
  for (int i = 0; i < 8; ++i) {
    ev[i] = __expf(ev[i] - mx);
    sum += ev[i];
  }
  for (int m = 1; m < 64; m <<= 1) sum += __shfl_xor(sum, m);
  if (lane == 0) wred[wid] = sum;
  __syncthreads();
  sum = wred[0] + wred[1] + wred[2] + wred[3];
  float inv = 1.f / sum;
#pragma unroll
  for (int i = 0; i < 8; ++i) {
    int s = tid + i * 256;
    float a = ev[i] * inv;
    A[b * kS + s] = a;
    newcov[b * kS + s] = coverage[b * kS + s] + a;
  }
}

// ------- context from TILED bf16 h_i (only valid when whole h_i tiled) ------
__global__ __launch_bounds__(256) void context_bf16_kernel(
    const __bf16* __restrict__ Atl, const float* __restrict__ A,
    float* __restrict__ C) {
  int b = blockIdx.x;
  int s0 = blockIdx.y * 256;
  int t = threadIdx.x;
  int kt = t >> 2, c = t & 3;
  float acc[8];
#pragma unroll
  for (int i = 0; i < 8; ++i) acc[i] = 0.f;
  for (int si = 0; si < 256; ++si) {
    int s = s0 + si;
    float a = A[b * kS + s];
    size_t mt16 = (size_t)b * 128 + (s >> 4);
    int sl = c ^ (((s >> 1)) & 3);
    size_t idx = (mt16 * 64 + kt) * 512 + (size_t)(((s & 15) * 4 + sl)) * 8;
    bf16x8_v v = *reinterpret_cast<const bf16x8_v*>(Atl + idx);
#pragma unroll
    for (int i = 0; i < 8; ++i) acc[i] += a * (float)v[i];
  }
  int d = kt * 32 + c * 8;
#pragma unroll
  for (int i = 0; i < 8; ++i) atomicAdd(&C[b * kD + d + i], acc[i]);
}

// ---------------- context from fp32 h_i (chunked fallback) ------------------
__global__ __launch_bounds__(256) void context_kernel(
    const float* __restrict__ h_i, const float* __restrict__ A,
    float* __restrict__ C) {
  int b = blockIdx.x;
  int d = blockIdx.y * 1024 + threadIdx.x * 4;
  int s0 = blockIdx.z * 256;
  const float* hp = h_i + ((size_t)b * kS + s0) * kD + d;
  const float* ap = A + b * kS + s0;
  float4 acc = {0.f, 0.f, 0.f, 0.f};
  for (int s = 0; s < 256; ++s) {
    float a = ap[s];
    float4 v = *reinterpret_cast<const float4*>(hp + (size_t)s * kD);
    acc.x += a * v.x;
    acc.y += a * v.y;
    acc.z += a * v.z;
    acc.w += a * v.w;
  }
  atomicAdd(&C[b * kD + d + 0], acc.x);
  atomicAdd(&C[b * kD + d + 1], acc.y);
  atomicAdd(&C[b * kD + d + 2], acc.z);
  atomicAdd(&C[b * kD + d + 3], acc.w);
}

extern "C" void kernel_launch(void* const* d_in, const int* in_sizes, int n_in,
                              void* d_out, int out_size, void* d_ws, size_t ws_size,
                              hipStream_t stream) {
  const float* s_t      = (const float*)d_in[0];
  const float* h_i      = (const float*)d_in[1];
  const float* coverage = (const float*)d_in[2];
  const float* W_h      = (const float*)d_in[3];
  const float* b_h      = (const float*)d_in[4];
  const float* W_s      = (const float*)d_in[5];
  const float* b_s      = (const float*)d_in[6];
  const float* W_c      = (const float*)d_in[7];
  const float* v_a      = (const float*)d_in[8];
  // d_in[9] = b_a: softmax-shift-invariant and E is not an output -> unused.

  float* out = (float*)d_out;
  float* C      = out;                 // (kB, kD)
  float* A      = out + kB * kD;       // (kB, kS)
  float* newcov = A + kB * kS;         // (kB, kS)

  // ---- adaptive chunking of the tiled-bf16 h_i buffer by ws_size
  size_t reserved = 8u << 20;          // Wtl 4MB + biasBH + E + slack
  size_t avail = ws_size > reserved ? ws_size - reserved : 0;
  int chunk_rows = 2048;
  for (long cr = (long)kM; cr >= 2048; cr >>= 1) {
    if ((size_t)cr * kD * 2 <= avail) { chunk_rows = (int)cr; break; }
  }
  int nchunks = kM / chunk_rows;

  char* ws = (char*)d_ws;
  __bf16* Atl   = (__bf16*)ws;                                  // chunked tiled A
  size_t atl_bytes = (size_t)chunk_rows * kD * 2;
  __bf16* Wtl   = (__bf16*)(ws + atl_bytes);                    // 4 MB tiled W_h
  float* biasBH = (float*)(ws + atl_bytes + (4u << 20));        // 256 KB
  float* E      = (float*)(ws + atl_bytes + (4u << 20) + (256u << 10));  // 512 KB

  hipMemsetAsync(E, 0, (size_t)kB * kS * sizeof(float), stream);
  hipMemsetAsync(C, 0, (size_t)kB * kD * sizeof(float), stream);

  conv_tile_kernel<<<kH, 256, 0, stream>>>(W_h, Wtl);
  prep_bias_kernel<<<(kB * kH) / 4, 256, 0, stream>>>(s_t, W_s, b_s, b_h, biasBH);

  for (int ch = 0; ch < nchunks; ++ch) {
    int mrow0 = ch * chunk_rows;
    conv_tile_kernel<<<chunk_rows, 256, 0, stream>>>(h_i + (size_t)mrow0 * kD, Atl);
    int mtiles = chunk_rows / 128;
    gemm_score_kernel<<<mtiles * 8, 256, 0, stream>>>(Atl, Wtl, biasBH, coverage,
                                                      W_c, v_a, E, mrow0);
  }

  softmax_kernel<<<kB, 256, 0, stream>>>(E, coverage, A, newcov);

  if (nchunks == 1) {
    dim3 gc(kB, kS / 256, 1);
    context_bf16_kernel<<<gc, 256, 0, stream>>>(Atl, A, C);
  } else {
    dim3 gc(kB, kD / 1024, kS / 256);
    context_kernel<<<gc, 256, 0, stream>>>(h_i, A, C);
  }
}

// Round 10
// 900.315 us; speedup vs baseline: 1.0823x; 1.0823x over previous
//
#include <hip/hip_runtime.h>
#include <hip/hip_bf16.h>

typedef __bf16 bf16x8_v __attribute__((ext_vector_type(8)));
typedef float  f32x4_v  __attribute__((ext_vector_type(4)));

static constexpr int kH = 1024;
static constexpr int kD = 2048;   // 2H
static constexpr int kB = 64;
static constexpr int kS = 2048;
static constexpr int kM = kB * kS;  // 131072 rows of the big GEMM

__device__ __forceinline__ void load_lds16(const void* g, void* l) {
  __builtin_amdgcn_global_load_lds(
      (const __attribute__((address_space(1))) unsigned int*)g,
      (__attribute__((address_space(3))) unsigned int*)l, 16, 0, 0);
}

__device__ __forceinline__ float fast_tanh(float x) {
  float e = __expf(2.0f * x);
  return 1.0f - 2.0f * __builtin_amdgcn_rcpf(e + 1.0f);
}

// ---- fp32 row-major [rows][2048] -> bf16 tiled ------------------------------
// Tile = 16 rows x 32 cols. Output: [row/16][kt=0..63][64 chunks of 16B].
// Chunk p: rr = p>>2, s = p&3; slot s holds k-chunk c = s ^ ((rr>>1)&3).
__global__ __launch_bounds__(256) void conv_tile_kernel(const float* __restrict__ in,
                                                        __bf16* __restrict__ out) {
  size_t g = (size_t)blockIdx.x * 256 + threadIdx.x;
  int p = (int)(g & 63);
  size_t tile = g >> 6;
  int kt = (int)(tile & 63);
  size_t mt16 = tile >> 6;
  int rr = p >> 2, s = p & 3;
  int c = s ^ ((rr >> 1) & 3);
  const float* src = in + (mt16 * 16 + rr) * (size_t)kD + kt * 32 + c * 8;
  float4 v0 = reinterpret_cast<const float4*>(src)[0];
  float4 v1 = reinterpret_cast<const float4*>(src)[1];
  bf16x8_v o = {(__bf16)v0.x, (__bf16)v0.y, (__bf16)v0.z, (__bf16)v0.w,
                (__bf16)v1.x, (__bf16)v1.y, (__bf16)v1.z, (__bf16)v1.w};
  reinterpret_cast<bf16x8_v*>(out)[g] = o;
}

// ------------- biasBH[b][h] = s_t[b] . W_s[h] + b_s[h] + b_h[h] -------------
__global__ __launch_bounds__(256) void prep_bias_kernel(
    const float* __restrict__ s_t, const float* __restrict__ W_s,
    const float* __restrict__ b_s, const float* __restrict__ b_h,
    float* __restrict__ biasBH) {
  int wave = blockIdx.x * 4 + (threadIdx.x >> 6);  // 65536 outputs
  int lane = threadIdx.x & 63;
  int b = wave >> 10, h = wave & 1023;
  const float4* sp = reinterpret_cast<const float4*>(s_t + (size_t)b * kD);
  const float4* wp = reinterpret_cast<const float4*>(W_s + (size_t)h * kD);
  float acc = 0.f;
  for (int i = lane; i < kD / 4; i += 64) {
    float4 a = sp[i], w = wp[i];
    acc += a.x * w.x + a.y * w.y + a.z * w.z + a.w * w.w;
  }
  for (int m = 1; m < 64; m <<= 1) acc += __shfl_xor(acc, m);
  if (lane == 0) biasBH[wave] = acc + b_s[h] + b_h[h];
}

// ---------------- big GEMM + fused tanh/v_a epilogue -> E -------------------
// (R8 structure, measured best.) BM=256, BN=128, BK=32, 8 waves (4M x 2N).
// Both operands staged via global_load_lds, 2-deep LDS (48 KB), counted
// vmcnt(3); 2 barriers/step; no VALU conversion in the loop.
__global__ __launch_bounds__(512, 4) void gemm_score_kernel(
    const __bf16* __restrict__ Atl,     // tiled bf16 A (chunk base)
    const __bf16* __restrict__ Btl,     // tiled bf16 W_h
    const float* __restrict__ biasBH,   // (kB, kH)
    const float* __restrict__ coverage, // (kB, kS)
    const float* __restrict__ Wc,       // (kH)
    const float* __restrict__ va,       // (kH)
    float* __restrict__ E,              // (kB, kS), pre-zeroed
    int mrow0) {                        // global row offset of this chunk
  const int bid = blockIdx.x;
  const int mtiles = gridDim.x >> 3;    // 256-row M-tiles in this chunk
  const int mpx = mtiles >> 3;
  const int xcd = bid & 7;
  const int slot = bid >> 3;
  const int m_l = xcd * mpx + (slot >> 3);  // XCD-partitioned, n fastest
  const int nblk = slot & 7;
  const int n0 = nblk * 128;
  const int m0l = m_l * 256;            // chunk-local row base
  const int m0g = mrow0 + m0l;          // global row base

  const int tid = threadIdx.x;
  const int lane = tid & 63;
  const int wid = tid >> 6;             // 0..7
  const int wm = wid >> 1, wn = wid & 1;

  __shared__ char lds[49152];           // 2 x (A 16K + B 8K)

  f32x4_v acc[4][4];
#pragma unroll
  for (int m = 0; m < 4; ++m)
#pragma unroll
    for (int n = 0; n < 4; ++n) acc[m][n] = {0.f, 0.f, 0.f, 0.f};

  const int rA = wm * 64 + (lane & 15);
  const int rB = wn * 64 + (lane & 15);
  const int slot16 = (((lane >> 4) ^ ((lane >> 1) & 3)) << 4);

  const size_t mt16b = (size_t)(m0l >> 4);      // first 16-row A tile
  const size_t nt16b = (size_t)(nblk * 8);      // first 16-row B tile

  // per-wave staging: A sub-tiles wid*2, wid*2+1 ; B sub-tile wid
  const __bf16* Asrc0 = Atl + ((mt16b + wid * 2) * 64) * 512 + lane * 8;
  const __bf16* Asrc1 = Atl + ((mt16b + wid * 2 + 1) * 64) * 512 + lane * 8;
  const __bf16* Bsrc  = Btl + ((nt16b + wid) * 64) * 512 + lane * 8;
  char* Adst0 = lds + wid * 2048;
  char* Adst1 = lds + wid * 2048 + 1024;
  char* Bdst  = lds + 16384 + wid * 1024;

#define STAGE(T)                                                  \
  do {                                                            \
    int boff = ((T) & 1) * 24576;                                 \
    load_lds16(Asrc0 + (size_t)(T) * 512, Adst0 + boff);          \
    load_lds16(Asrc1 + (size_t)(T) * 512, Adst1 + boff);          \
    load_lds16(Bsrc + (size_t)(T) * 512, Bdst + boff);            \
  } while (0)

  STAGE(0);
  STAGE(1);

#pragma unroll 2
  for (int t = 0; t < 64; ++t) {
    if (t < 63) asm volatile("s_waitcnt vmcnt(3)" ::: "memory");
    else        asm volatile("s_waitcnt vmcnt(0)" ::: "memory");
    __builtin_amdgcn_s_barrier();
    asm volatile("" ::: "memory");

    const char* Ab = lds + (t & 1) * 24576;
    const char* Bb = Ab + 16384;
    bf16x8_v a[4], b[4];
#pragma unroll
    for (int m = 0; m < 4; ++m)
      a[m] = *reinterpret_cast<const bf16x8_v*>(Ab + (rA + m * 16) * 64 + slot16);
#pragma unroll
    for (int n = 0; n < 4; ++n)
      b[n] = *reinterpret_cast<const bf16x8_v*>(Bb + (rB + n * 16) * 64 + slot16);
    __builtin_amdgcn_s_setprio(1);
#pragma unroll
    for (int m = 0; m < 4; ++m)
#pragma unroll
      for (int n = 0; n < 4; ++n)
        acc[m][n] = __builtin_amdgcn_mfma_f32_16x16x32_bf16(a[m], b[n], acc[m][n], 0, 0, 0);
    __builtin_amdgcn_s_setprio(0);

    asm volatile("s_waitcnt lgkmcnt(0)" ::: "memory");
    __builtin_amdgcn_s_barrier();
    asm volatile("" ::: "memory");
    if (t + 2 < 64) STAGE(t + 2);
  }
#undef STAGE

  // ---- epilogue: z = acc + bias + cov*Wc; E_partial = sum_h tanh(z)*va[h]
  const int bb = m0g >> 11;
  const int colg = lane & 15;
  const int rowg = lane >> 4;           // 0..3
  float bias_v[4], wc_v[4], va_v[4];
#pragma unroll
  for (int n = 0; n < 4; ++n) {
    int h = n0 + wn * 64 + n * 16 + colg;
    bias_v[n] = biasBH[bb * kH + h];
    wc_v[n] = Wc[h];
    va_v[n] = va[h];
  }
  const int s_tile = (m0g & (kS - 1));
  float rowsum[4][4];
#pragma unroll
  for (int m = 0; m < 4; ++m)
#pragma unroll
    for (int q = 0; q < 4; ++q) rowsum[m][q] = 0.f;

#pragma unroll
  for (int m = 0; m < 4; ++m) {
    int sbase = s_tile + wm * 64 + m * 16 + rowg * 4;
    float cov[4];
#pragma unroll
    for (int q = 0; q < 4; ++q) cov[q] = coverage[bb * kS + sbase + q];
#pragma unroll
    for (int n = 0; n < 4; ++n) {
#pragma unroll
      for (int q = 0; q < 4; ++q) {
        float z = acc[m][n][q] + bias_v[n] + cov[q] * wc_v[n];
        rowsum[m][q] += fast_tanh(z) * va_v[n];
      }
    }
  }
#pragma unroll
  for (int m = 0; m < 4; ++m) {
#pragma unroll
    for (int q = 0; q < 4; ++q) {
      float v = rowsum[m][q];
      v += __shfl_xor(v, 1);
      v += __shfl_xor(v, 2);
      v += __shfl_xor(v, 4);
      v += __shfl_xor(v, 8);
      if (colg == 0) {
        int s = s_tile + wm * 64 + m * 16 + rowg * 4 + q;
        atomicAdd(&E[bb * kS + s], v);
      }
    }
  }
}

// ---------------- softmax over S per (b); A and new_cov ---------------------
__global__ __launch_bounds__(256) void softmax_kernel(
    const float* __restrict__ E, const float* __restrict__ coverage,
    float* __restrict__ A, float* __restrict__ newcov) {
  int b = blockIdx.x;
  int tid = threadIdx.x;
  int wid = tid >> 6, lane = tid & 63;
  __shared__ float wred[4];
  float ev[8];
  float mx = -INFINITY;
#pragma unroll
  for (int i = 0; i < 8; ++i) {
    ev[i] = E[b * kS + tid + i * 256];
    mx = fmaxf(mx, ev[i]);
  }
  for (int m = 1; m < 64; m <<= 1) mx = fmaxf(mx, __shfl_xor(mx, m));
  if (lane == 0) wred[wid] = mx;
  __syncthreads();
  mx = fmaxf(fmaxf(wred[0], wred[1]), fmaxf(wred[2], wred[3]));
  __syncthreads();
  float sum = 0.f;
#pragma unroll
  for (int i = 0; i < 8; ++i) {
    ev[i] = __expf(ev[i] - mx);
    sum += ev[i];
  }
  for (int m = 1; m < 64; m <<= 1) sum += __shfl_xor(sum, m);
  if (lane == 0) wred[wid] = sum;
  __syncthreads();
  sum = wred[0] + wred[1] + wred[2] + wred[3];
  float inv = 1.f / sum;
#pragma unroll
  for (int i = 0; i < 8; ++i) {
    int s = tid + i * 256;
    float a = ev[i] * inv;
    A[b * kS + s] = a;
    newcov[b * kS + s] = coverage[b * kS + s] + a;
  }
}

// ------- context from TILED bf16 h_i (full tiled buffer) --------------------
__global__ __launch_bounds__(256) void context_bf16_kernel(
    const __bf16* __restrict__ Atl, const float* __restrict__ A,
    float* __restrict__ C) {
  int b = blockIdx.x;
  int s0 = blockIdx.y * 256;
  int t = threadIdx.x;
  int kt = t >> 2, c = t & 3;
  float acc[8];
#pragma unroll
  for (int i = 0; i < 8; ++i) acc[i] = 0.f;
  for (int si = 0; si < 256; ++si) {
    int s = s0 + si;
    float a = A[b * kS + s];
    size_t mt16 = (size_t)b * 128 + (s >> 4);
    int sl = c ^ (((s >> 1)) & 3);
    size_t idx = (mt16 * 64 + kt) * 512 + (size_t)(((s & 15) * 4 + sl)) * 8;
    bf16x8_v v = *reinterpret_cast<const bf16x8_v*>(Atl + idx);
#pragma unroll
    for (int i = 0; i < 8; ++i) acc[i] += a * (float)v[i];
  }
  int d = kt * 32 + c * 8;
#pragma unroll
  for (int i = 0; i < 8; ++i) atomicAdd(&C[b * kD + d + i], acc[i]);
}

// ---------------- context from fp32 h_i (small-ws fallback) -----------------
__global__ __launch_bounds__(256) void context_kernel(
    const float* __restrict__ h_i, const float* __restrict__ A,
    float* __restrict__ C) {
  int b = blockIdx.x;
  int d = blockIdx.y * 1024 + threadIdx.x * 4;
  int s0 = blockIdx.z * 256;
  const float* hp = h_i + ((size_t)b * kS + s0) * kD + d;
  const float* ap = A + b * kS + s0;
  float4 acc = {0.f, 0.f, 0.f, 0.f};
  for (int s = 0; s < 256; ++s) {
    float a = ap[s];
    float4 v = *reinterpret_cast<const float4*>(hp + (size_t)s * kD);
    acc.x += a * v.x;
    acc.y += a * v.y;
    acc.z += a * v.z;
    acc.w += a * v.w;
  }
  atomicAdd(&C[b * kD + d + 0], acc.x);
  atomicAdd(&C[b * kD + d + 1], acc.y);
  atomicAdd(&C[b * kD + d + 2], acc.z);
  atomicAdd(&C[b * kD + d + 3], acc.w);
}

extern "C" void kernel_launch(void* const* d_in, const int* in_sizes, int n_in,
                              void* d_out, int out_size, void* d_ws, size_t ws_size,
                              hipStream_t stream) {
  const float* s_t      = (const float*)d_in[0];
  const float* h_i      = (const float*)d_in[1];
  const float* coverage = (const float*)d_in[2];
  const float* W_h      = (const float*)d_in[3];
  const float* b_h      = (const float*)d_in[4];
  const float* W_s      = (const float*)d_in[5];
  const float* b_s      = (const float*)d_in[6];
  const float* W_c      = (const float*)d_in[7];
  const float* v_a      = (const float*)d_in[8];
  // d_in[9] = b_a: softmax-shift-invariant and E is not an output -> unused.

  float* out = (float*)d_out;
  float* C      = out;                 // (kB, kD)
  float* A      = out + kB * kD;       // (kB, kS)
  float* newcov = A + kB * kS;         // (kB, kS)

  // ---- Atl sizing: full 512 MB if ws allows, else largest power-of-2 chunk
  size_t reserved = 8u << 20;          // Wtl 4MB + biasBH + E + slack
  size_t avail = ws_size > reserved ? ws_size - reserved : 0;
  int alloc_rows = 2048;
  for (long cr = (long)kM; cr >= 2048; cr >>= 1) {
    if ((size_t)cr * kD * 2 <= avail) { alloc_rows = (int)cr; break; }
  }
  bool full = (alloc_rows == kM);
  // conv/GEMM processing chunk: 32768 rows (128 MB tiled, L3-resident) so the
  // GEMM's A-reads hit L3 right after conv writes them.
  int proc_rows = full ? 32768 : alloc_rows;
  int nchunks = kM / proc_rows;

  char* ws = (char*)d_ws;
  __bf16* Atl   = (__bf16*)ws;
  size_t atl_bytes = (size_t)alloc_rows * kD * 2;
  __bf16* Wtl   = (__bf16*)(ws + atl_bytes);                    // 4 MB tiled W_h
  float* biasBH = (float*)(ws + atl_bytes + (4u << 20));        // 256 KB
  float* E      = (float*)(ws + atl_bytes + (4u << 20) + (256u << 10));  // 512 KB

  hipMemsetAsync(E, 0, (size_t)kB * kS * sizeof(float), stream);
  hipMemsetAsync(C, 0, (size_t)kB * kD * sizeof(float), stream);

  conv_tile_kernel<<<kH, 256, 0, stream>>>(W_h, Wtl);
  prep_bias_kernel<<<(kB * kH) / 4, 256, 0, stream>>>(s_t, W_s, b_s, b_h, biasBH);

  for (int ch = 0; ch < nchunks; ++ch) {
    int mrow0 = ch * proc_rows;
    __bf16* Atl_ch = full ? (Atl + (size_t)mrow0 * kD) : Atl;
    conv_tile_kernel<<<proc_rows, 256, 0, stream>>>(h_i + (size_t)mrow0 * kD, Atl_ch);
    int mtiles = proc_rows / 256;
    gemm_score_kernel<<<mtiles * 8, 512, 0, stream>>>(Atl_ch, Wtl, biasBH, coverage,
                                                      W_c, v_a, E, mrow0);
  }

  softmax_kernel<<<kB, 256, 0, stream>>>(E, coverage, A, newcov);

  if (full) {
    dim3 gc(kB, kS / 256, 1);
    context_bf16_kernel<<<gc, 256, 0, stream>>>(Atl, A, C);
  } else {
    dim3 gc(kB, kD / 1024, kS / 256);
    context_kernel<<<gc, 256, 0, stream>>>(h_i, A, C);
  }
}

// Round 11
// 850.496 us; speedup vs baseline: 1.1457x; 1.0586x over previous
//
#include <hip/hip_runtime.h>
#include <hip/hip_bf16.h>

typedef __bf16 bf16x8_v __attribute__((ext_vector_type(8)));
typedef float  f32x4_v  __attribute__((ext_vector_type(4)));

static constexpr int kH = 1024;
static constexpr int kD = 2048;   // 2H
static constexpr int kB = 64;
static constexpr int kS = 2048;
static constexpr int kM = kB * kS;  // 131072 rows of the big GEMM

__device__ __forceinline__ void load_lds16(const void* g, void* l) {
  __builtin_amdgcn_global_load_lds(
      (const __attribute__((address_space(1))) unsigned int*)g,
      (__attribute__((address_space(3))) unsigned int*)l, 16, 0, 0);
}

__device__ __forceinline__ float fast_tanh(float x) {
  float e = __expf(2.0f * x);
  return 1.0f - 2.0f * __builtin_amdgcn_rcpf(e + 1.0f);
}

// ---- W_h fp32 -> bf16 tiled (16x32 subtiles, XOR slot swizzle) -------------
// Output: [h/16][kt=0..63][64 chunks of 16B]. Chunk p: rr=p>>2, s=p&3;
// slot s holds k-chunk c = s ^ ((rr>>1)&3)  (read side: slot16 XOR, R8-proven).
__global__ __launch_bounds__(256) void conv_tile_kernel(const float* __restrict__ in,
                                                        __bf16* __restrict__ out) {
  size_t g = (size_t)blockIdx.x * 256 + threadIdx.x;
  int p = (int)(g & 63);
  size_t tile = g >> 6;
  int kt = (int)(tile & 63);
  size_t mt16 = tile >> 6;
  int rr = p >> 2, s = p & 3;
  int c = s ^ ((rr >> 1) & 3);
  const float* src = in + (mt16 * 16 + rr) * (size_t)kD + kt * 32 + c * 8;
  float4 v0 = reinterpret_cast<const float4*>(src)[0];
  float4 v1 = reinterpret_cast<const float4*>(src)[1];
  bf16x8_v o = {(__bf16)v0.x, (__bf16)v0.y, (__bf16)v0.z, (__bf16)v0.w,
                (__bf16)v1.x, (__bf16)v1.y, (__bf16)v1.z, (__bf16)v1.w};
  reinterpret_cast<bf16x8_v*>(out)[g] = o;
}

// ------------- biasBH[b][h] = s_t[b] . W_s[h] + b_s[h] + b_h[h] -------------
__global__ __launch_bounds__(256) void prep_bias_kernel(
    const float* __restrict__ s_t, const float* __restrict__ W_s,
    const float* __restrict__ b_s, const float* __restrict__ b_h,
    float* __restrict__ biasBH) {
  int wave = blockIdx.x * 4 + (threadIdx.x >> 6);  // 65536 outputs
  int lane = threadIdx.x & 63;
  int b = wave >> 10, h = wave & 1023;
  const float4* sp = reinterpret_cast<const float4*>(s_t + (size_t)b * kD);
  const float4* wp = reinterpret_cast<const float4*>(W_s + (size_t)h * kD);
  float acc = 0.f;
  for (int i = lane; i < kD / 4; i += 64) {
    float4 a = sp[i], w = wp[i];
    acc += a.x * w.x + a.y * w.y + a.z * w.z + a.w * w.w;
  }
  for (int m = 1; m < 64; m <<= 1) acc += __shfl_xor(acc, m);
  if (lane == 0) biasBH[wave] = acc + b_s[h] + b_h[h];
}

// ---------------- big GEMM + fused tanh/v_a epilogue -> E -------------------
// BM=256, BN=256, BK=32 (64 K-tiles), 8 waves (2M x 4N), per-wave 128x64.
// A: raw fp32 h_i staged via global_load_lds with per-lane XOR-swizzled
//    SOURCE addresses (chunk c of row r lands at LDS chunk c^(r&7); dest
//    linear) -> conflict-free f32x4 fragment reads; fp32->bf16 AFTER ds_read.
// B: pre-tiled bf16 W_h (conv_tile_kernel), R8's proven slot16 XOR reads.
// 3-deep LDS (3 x 48 KB = 144 KB, 1 block/CU), stage 2 tiles ahead,
// ONE barrier + ONE counted vmcnt(6) per K-tile (never drained mid-loop).
// Correctness: each wave waits vmcnt(6) (own 6 stage(t) loads oldest) then
// barriers; all waves passing the barrier => stage(t) fully landed. Stage(t+2)
// overwrites buf((t+2)%3)=buf((t-1)%3), whose reads finished before this
// barrier in every wave's program order.
__global__ __launch_bounds__(512, 2) void gemm_score_kernel(
    const float* __restrict__ h_i,      // (kM, kD) fp32
    const __bf16* __restrict__ Wtl,     // tiled bf16 W_h
    const float* __restrict__ biasBH,   // (kB, kH)
    const float* __restrict__ coverage, // (kB, kS)
    const float* __restrict__ Wc,       // (kH)
    const float* __restrict__ va,       // (kH)
    float* __restrict__ E) {            // (kB, kS), pre-zeroed
  const int bid = blockIdx.x;           // 2048 blocks
  const int xcd = bid & 7;
  const int slot = bid >> 3;
  const int n0 = (slot & 3) * 256;      // 4 N-tiles, fastest within XCD
  const int m0 = (xcd * 64 + (slot >> 2)) * 256;

  const int tid = threadIdx.x;
  const int lane = tid & 63;
  const int wid = tid >> 6;             // 0..7
  const int wm = wid >> 2, wn = wid & 3;

  __shared__ char lds[3 * 49152];       // per buf: A fp32 32K + B bf16 16K

  f32x4_v acc[8][4];
#pragma unroll
  for (int m = 0; m < 8; ++m)
#pragma unroll
    for (int n = 0; n < 4; ++n) acc[m][n] = {0.f, 0.f, 0.f, 0.f};

  const int l15 = lane & 15;
  const int j = lane >> 4;              // k-group 0..3
  const int s7 = lane & 7;
  const int aco0 = ((2 * j) ^ s7) << 4; // A chunk byte offsets (XOR family)
  const int aco1 = aco0 ^ 16;
  const int slot16 = ((j ^ ((l15 >> 1) & 3)) << 4);  // B read swizzle (R8)

  // ---- staging geometry (wave-uniform LDS dest, per-lane global src)
  // A: wave wid stages windows wid*4+w (w<4); window = 8 rows x 8 chunks = 1KB
  const int awr = lane >> 3;            // row within window 0..7
  const int awc = (lane & 7) ^ awr;     // src chunk for this lane (inverse XOR)
  const float* Asrc[4];
  char* Adst[4];
#pragma unroll
  for (int w = 0; w < 4; ++w) {
    int win = wid * 4 + w;
    Asrc[w] = h_i + (size_t)(m0 + win * 8 + awr) * kD + awc * 4;
    Adst[w] = (char*)lds + win * 1024;
  }
  // B: wave wid stages subtiles wid*2+s (s<2), 1KB each
  const int nt16b = (slot & 3) * 16;
  const __bf16* Bsrc[2];
  char* Bdst[2];
#pragma unroll
  for (int s = 0; s < 2; ++s) {
    Bsrc[s] = Wtl + ((size_t)(nt16b + wid * 2 + s) * 64) * 512 + lane * 8;
    Bdst[s] = (char*)lds + 32768 + (wid * 2 + s) * 1024;
  }

#define STAGE(T)                                                       \
  do {                                                                 \
    int bo = ((T) % 3) * 49152;                                        \
    load_lds16(Asrc[0] + (T) * 32, Adst[0] + bo);                      \
    load_lds16(Asrc[1] + (T) * 32, Adst[1] + bo);                      \
    load_lds16(Asrc[2] + (T) * 32, Adst[2] + bo);                      \
    load_lds16(Asrc[3] + (T) * 32, Adst[3] + bo);                      \
    load_lds16(Bsrc[0] + (size_t)(T) * 512, Bdst[0] + bo);             \
    load_lds16(Bsrc[1] + (size_t)(T) * 512, Bdst[1] + bo);             \
  } while (0)

#define RD_A(AF, I, AB)                                                          \
  do {                                                                           \
    int row = wm * 128 + (I) * 16 + l15;                                         \
    const char* base = (AB) + row * 128;                                         \
    f32x4_v lo = *reinterpret_cast<const f32x4_v*>(base + aco0);                 \
    f32x4_v hi = *reinterpret_cast<const f32x4_v*>(base + aco1);                 \
    AF = bf16x8_v{(__bf16)lo[0], (__bf16)lo[1], (__bf16)lo[2], (__bf16)lo[3],    \
                  (__bf16)hi[0], (__bf16)hi[1], (__bf16)hi[2], (__bf16)hi[3]};   \
  } while (0)

#define TILE(T, DO_STAGE, WAITN)                                       \
  do {                                                                 \
    asm volatile("s_waitcnt vmcnt(" #WAITN ")" ::: "memory");          \
    __builtin_amdgcn_s_barrier();                                      \
    asm volatile("" ::: "memory");                                     \
    if (DO_STAGE) STAGE((T) + 2);                                      \
    const char* Ab = (const char*)lds + ((T) % 3) * 49152;             \
    const char* Bb = Ab + 32768;                                       \
    bf16x8_v b[4];                                                     \
    _Pragma("unroll")                                                  \
    for (int n = 0; n < 4; ++n) {                                      \
      int row = wn * 64 + n * 16 + l15;                                \
      b[n] = *reinterpret_cast<const bf16x8_v*>(                       \
          Bb + (row >> 4) * 1024 + (row & 15) * 64 + slot16);          \
    }                                                                  \
    bf16x8_v a0, a1, a2, a3;                                           \
    RD_A(a0, 0, Ab); RD_A(a1, 1, Ab); RD_A(a2, 2, Ab); RD_A(a3, 3, Ab);\
    __builtin_amdgcn_s_setprio(1);                                     \
    _Pragma("unroll")                                                  \
    for (int n = 0; n < 4; ++n) {                                      \
      acc[0][n] = __builtin_amdgcn_mfma_f32_16x16x32_bf16(a0, b[n], acc[0][n], 0, 0, 0); \
      acc[1][n] = __builtin_amdgcn_mfma_f32_16x16x32_bf16(a1, b[n], acc[1][n], 0, 0, 0); \
      acc[2][n] = __builtin_amdgcn_mfma_f32_16x16x32_bf16(a2, b[n], acc[2][n], 0, 0, 0); \
      acc[3][n] = __builtin_amdgcn_mfma_f32_16x16x32_bf16(a3, b[n], acc[3][n], 0, 0, 0); \
    }                                                                  \
    __builtin_amdgcn_s_setprio(0);                                     \
    RD_A(a0, 4, Ab); RD_A(a1, 5, Ab); RD_A(a2, 6, Ab); RD_A(a3, 7, Ab);\
    __builtin_amdgcn_s_setprio(1);                                     \
    _Pragma("unroll")                                                  \
    for (int n = 0; n < 4; ++n) {                                      \
      acc[4][n] = __builtin_amdgcn_mfma_f32_16x16x32_bf16(a0, b[n], acc[4][n], 0, 0, 0); \
      acc[5][n] = __builtin_amdgcn_mfma_f32_16x16x32_bf16(a1, b[n], acc[5][n], 0, 0, 0); \
      acc[6][n] = __builtin_amdgcn_mfma_f32_16x16x32_bf16(a2, b[n], acc[6][n], 0, 0, 0); \
      acc[7][n] = __builtin_amdgcn_mfma_f32_16x16x32_bf16(a3, b[n], acc[7][n], 0, 0, 0); \
    }                                                                  \
    __builtin_amdgcn_s_setprio(0);                                     \
  } while (0)

  // prologue: stage tiles 0,1
  STAGE(0);
  STAGE(1);

  for (int t = 0; t < 60; t += 3) {
    TILE(t, 1, 6);
    TILE(t + 1, 1, 6);
    TILE(t + 2, 1, 6);
  }
  TILE(60, 1, 6);   // stages 62
  TILE(61, 1, 6);   // stages 63
  TILE(62, 0, 6);
  TILE(63, 0, 0);

#undef STAGE
#undef RD_A
#undef TILE

  // ---- epilogue: z = acc + bias + cov*Wc; E_partial = sum_h tanh(z)*va[h]
  const int bb = m0 >> 11;              // batch (uniform per block)
  const int colg = lane & 15;
  const int rowg = lane >> 4;           // 0..3
  float bias_v[4], wc_v[4], va_v[4];
#pragma unroll
  for (int n = 0; n < 4; ++n) {
    int h = n0 + wn * 64 + n * 16 + colg;
    bias_v[n] = biasBH[bb * kH + h];
    wc_v[n] = Wc[h];
    va_v[n] = va[h];
  }
  const int s_tile = (m0 & (kS - 1));
#pragma unroll
  for (int m = 0; m < 8; ++m) {
    int sbase = s_tile + wm * 128 + m * 16 + rowg * 4;
    float cov[4], rowsum[4];
#pragma unroll
    for (int q = 0; q < 4; ++q) {
      cov[q] = coverage[bb * kS + sbase + q];
      rowsum[q] = 0.f;
    }
#pragma unroll
    for (int n = 0; n < 4; ++n) {
#pragma unroll
      for (int q = 0; q < 4; ++q) {
        float z = acc[m][n][q] + bias_v[n] + cov[q] * wc_v[n];
        rowsum[q] += fast_tanh(z) * va_v[n];
      }
    }
#pragma unroll
    for (int q = 0; q < 4; ++q) {
      float v = rowsum[q];
      v += __shfl_xor(v, 1);
      v += __shfl_xor(v, 2);
      v += __shfl_xor(v, 4);
      v += __shfl_xor(v, 8);
      if (colg == 0) atomicAdd(&E[bb * kS + sbase + q], v);
    }
  }
}

// ---------------- softmax over S per (b); A and new_cov ---------------------
__global__ __launch_bounds__(256) void softmax_kernel(
    const float* __restrict__ E, const float* __restrict__ coverage,
    float* __restrict__ A, float* __restrict__ newcov) {
  int b = blockIdx.x;
  int tid = threadIdx.x;
  int wid = tid >> 6, lane = tid & 63;
  __shared__ float wred[4];
  float ev[8];
  float mx = -INFINITY;
#pragma unroll
  for (int i = 0; i < 8; ++i) {
    ev[i] = E[b * kS + tid + i * 256];
    mx = fmaxf(mx, ev[i]);
  }
  for (int m = 1; m < 64; m <<= 1) mx = fmaxf(mx, __shfl_xor(mx, m));
  if (lane == 0) wred[wid] = mx;
  __syncthreads();
  mx = fmaxf(fmaxf(wred[0], wred[1]), fmaxf(wred[2], wred[3]));
  __syncthreads();
  float sum = 0.f;
#pragma unroll
  for (int i = 0; i < 8; ++i) {
    ev[i] = __expf(ev[i] - mx);
    sum += ev[i];
  }
  for (int m = 1; m < 64; m <<= 1) sum += __shfl_xor(sum, m);
  if (lane == 0) wred[wid] = sum;
  __syncthreads();
  sum = wred[0] + wred[1] + wred[2] + wred[3];
  float inv = 1.f / sum;
#pragma unroll
  for (int i = 0; i < 8; ++i) {
    int s = tid + i * 256;
    float a = ev[i] * inv;
    A[b * kS + s] = a;
    newcov[b * kS + s] = coverage[b * kS + s] + a;
  }
}

// ---------------- context C[b] = sum_s A[b,s] * h_i[b,s,:] ------------------
__global__ __launch_bounds__(256) void context_kernel(
    const float* __restrict__ h_i, const float* __restrict__ A,
    float* __restrict__ C) {
  int b = blockIdx.x;
  int d = blockIdx.y * 1024 + threadIdx.x * 4;
  int s0 = blockIdx.z * 256;
  const float* hp = h_i + ((size_t)b * kS + s0) * kD + d;
  const float* ap = A + b * kS + s0;
  float4 acc = {0.f, 0.f, 0.f, 0.f};
  for (int s = 0; s < 256; ++s) {
    float a = ap[s];
    float4 v = *reinterpret_cast<const float4*>(hp + (size_t)s * kD);
    acc.x += a * v.x;
    acc.y += a * v.y;
    acc.z += a * v.z;
    acc.w += a * v.w;
  }
  atomicAdd(&C[b * kD + d + 0], acc.x);
  atomicAdd(&C[b * kD + d + 1], acc.y);
  atomicAdd(&C[b * kD + d + 2], acc.z);
  atomicAdd(&C[b * kD + d + 3], acc.w);
}

extern "C" void kernel_launch(void* const* d_in, const int* in_sizes, int n_in,
                              void* d_out, int out_size, void* d_ws, size_t ws_size,
                              hipStream_t stream) {
  const float* s_t      = (const float*)d_in[0];
  const float* h_i      = (const float*)d_in[1];
  const float* coverage = (const float*)d_in[2];
  const float* W_h      = (const float*)d_in[3];
  const float* b_h      = (const float*)d_in[4];
  const float* W_s      = (const float*)d_in[5];
  const float* b_s      = (const float*)d_in[6];
  const float* W_c      = (const float*)d_in[7];
  const float* v_a      = (const float*)d_in[8];
  // d_in[9] = b_a: softmax-shift-invariant and E is not an output -> unused.

  float* out = (float*)d_out;
  float* C      = out;                 // (kB, kD)
  float* A      = out + kB * kD;       // (kB, kS)
  float* newcov = A + kB * kS;         // (kB, kS)

  char* ws = (char*)d_ws;
  __bf16* Wtl   = (__bf16*)ws;                                // 4 MB tiled W_h
  float* biasBH = (float*)(ws + (4u << 20));                  // 256 KB
  float* E      = (float*)(ws + (4u << 20) + (256u << 10));   // 512 KB

  hipMemsetAsync(E, 0, (size_t)kB * kS * sizeof(float), stream);
  hipMemsetAsync(C, 0, (size_t)kB * kD * sizeof(float), stream);

  conv_tile_kernel<<<kH, 256, 0, stream>>>(W_h, Wtl);
  prep_bias_kernel<<<(kB * kH) / 4, 256, 0, stream>>>(s_t, W_s, b_s, b_h, biasBH);

  gemm_score_kernel<<<2048, 512, 0, stream>>>(h_i, Wtl, biasBH, coverage,
                                              W_c, v_a, E);

  softmax_kernel<<<kB, 256, 0, stream>>>(E, coverage, A, newcov);

  dim3 gc(kB, kD / 1024, kS / 256);
  context_kernel<<<gc, 256, 0, stream>>>(h_i, A, C);
}